// Round 6
// baseline (651.348 us; speedup 1.0000x reference)
//
#include <hip/hip_runtime.h>
#include <hip/hip_cooperative_groups.h>

// FloodPath R6: single cooperative kernel, 3 grid.sync phases, SAFE grid.
//   A pack:   float2 [H][W][2] -> occ/flood bit planes, column-major [w][r].
//   B flood:  64x224 tiles, 16 bit-parallel dilation steps (2 words/thread in
//             regs, LDS vertical exchange), writes flood + 5 count planes.
//   C expand: planes + flood_count -> float3 out, streaming.
// R5 failed: 1216-block cooperative launch rejected by occupancy validation
// (silent error, output stayed zero). Fix: 512 blocks (>=2x co-residency
// margin at any plausible VGPR count), grid-stride phases.

typedef unsigned long long u64;
namespace cg = cooperative_groups;

#define HH 4096
#define WW 4096
#define WPR 64            // u64 words per image row
#define NSTEPS 16
#define NBLK 512          // cooperative grid (safe co-residency)
#define NTILES 1216       // 64 word-cols x 19 row-tiles
#define VROWS 224         // interior rows per flood tile
#define RROWS 256         // region rows = VROWS + 2*16

__global__ __launch_bounds__(256, 4) void fused_kernel(
    const float* __restrict__ in, const float* __restrict__ fcount,
    float* __restrict__ out,
    u64* __restrict__ occP, u64* __restrict__ flP, u64* __restrict__ planes)
{
    __shared__ u64 bufA[RROWS * 2];
    __shared__ u64 bufB[RROWS * 2];
    cg::grid_group grid = cg::this_grid();

    const int tid  = threadIdx.x;
    const int lane = tid & 63;
    const int wv   = tid >> 6;
    const int bid  = blockIdx.x;
    const size_t P = (size_t)WPR * HH;

    // ---------------- Phase A: bitpack ----------------
    for (int r = bid; r < HH; r += NBLK) {
#pragma unroll
        for (int b = 0; b < 2; ++b) {
            float vx[8], vy[8];
#pragma unroll
            for (int j = 0; j < 8; ++j) {
                const int w = wv * 16 + b * 8 + j;
                const float2 v = *(const float2*)(in + ((size_t)r * WW + (w << 6) + lane) * 2);
                vx[j] = v.x; vy[j] = v.y;
            }
#pragma unroll
            for (int j = 0; j < 8; ++j) {
                const int w = wv * 16 + b * 8 + j;
                const u64 om = __ballot(vx[j] > 0.5f);
                const u64 fm = __ballot(vy[j] > 0.5f);
                if (lane == 0) {
                    occP[(size_t)w * HH + r] = om;   // [w][r]
                    flP [(size_t)w * HH + r] = fm;
                }
            }
        }
    }
    __threadfence();
    grid.sync();

    // ---------------- Phase B: flood iterate (grid-stride over tiles) ------
    for (int t = bid; t < NTILES; t += NBLK) {
        const int w  = t & 63;                    // interior word column
        const int ty = t >> 6;                    // row tile 0..18
        const int gr = ty * VROWS + tid - 16;
        const bool rin = (gr >= 0) && (gr < HH);

        u64 oc[3], fl[3];
#pragma unroll
        for (int j = 0; j < 3; ++j) {
            const int q = w - 1 + j;
            const bool v = rin && (q >= 0) && (q < WPR);
            oc[j] = v ? occP[(size_t)q * HH + gr] : ~0ull;   // OOB => wall
            fl[j] = v ? flP [(size_t)q * HH + gr] : 0ull;
        }
        const u64 nocc0 = ~((oc[0] >> 48) | (oc[1] << 16));
        const u64 nocc1 = ~((oc[1] >> 48) | (oc[2] << 16));
        u64 f0 = (fl[0] >> 48) | (fl[1] << 16);
        u64 f1 = (fl[1] >> 48) | (fl[2] << 16);

        u64 c00 = 0, c01 = 0, c02 = 0, c03 = 0, c04 = 0;
        u64 c10 = 0, c11 = 0, c12 = 0, c13 = 0, c14 = 0;

        __syncthreads();                          // bufA free from prior tile
        bufA[tid * 2 + 0] = f0; bufA[tid * 2 + 1] = f1;
        __syncthreads();

        u64* cur = bufA;
        u64* nxt = bufB;
        for (int it = 0; it < NSTEPS; ++it) {
            u64 up0 = 0, up1 = 0, dn0 = 0, dn1 = 0;
            if (tid > 0)         { up0 = cur[(tid - 1) * 2 + 0]; up1 = cur[(tid - 1) * 2 + 1]; }
            if (tid < RROWS - 1) { dn0 = cur[(tid + 1) * 2 + 0]; dn1 = cur[(tid + 1) * 2 + 1]; }
            const u64 nf0 = nocc0 & (f0 | (f0 << 1) | (f0 >> 1) | (f1 << 63) | up0 | dn0);
            const u64 nf1 = nocc1 & (f1 | (f1 << 1) | (f0 >> 63) | (f1 >> 1) | up1 | dn1);
            u64 c, tt;
            c = nf0;
            tt = c00; c00 = tt ^ c; c = tt & c;
            tt = c01; c01 = tt ^ c; c = tt & c;
            tt = c02; c02 = tt ^ c; c = tt & c;
            tt = c03; c03 = tt ^ c; c = tt & c;
            c04 ^= c;                              // max 16: no carry out
            c = nf1;
            tt = c10; c10 = tt ^ c; c = tt & c;
            tt = c11; c11 = tt ^ c; c = tt & c;
            tt = c12; c12 = tt ^ c; c = tt & c;
            tt = c13; c13 = tt ^ c; c = tt & c;
            c14 ^= c;
            nxt[tid * 2 + 0] = nf0; nxt[tid * 2 + 1] = nf1;
            f0 = nf0; f1 = nf1;
            __syncthreads();
            u64* tmp = cur; cur = nxt; nxt = tmp;
        }

        if (tid >= 16 && tid < 16 + VROWS && gr < HH) {
            const size_t o = (size_t)w * HH + gr;
            planes[o]         = (f0  >> 16) | (f1  << 48);
            planes[P + o]     = (c00 >> 16) | (c10 << 48);
            planes[2 * P + o] = (c01 >> 16) | (c11 << 48);
            planes[3 * P + o] = (c02 >> 16) | (c12 << 48);
            planes[4 * P + o] = (c03 >> 16) | (c13 << 48);
            planes[5 * P + o] = (c04 >> 16) | (c14 << 48);
        }
    }
    __threadfence();
    grid.sync();

    // ---------------- Phase C: expand (streaming) ----------------
    for (int r = bid; r < HH; r += NBLK) {
#pragma unroll 2
        for (int i = 0; i < 16; ++i) {
            const int w2 = wv * 16 + i;            // word along the row
            const size_t o = (size_t)w2 * HH + r;
            const u64 ow = occP[o];
            const u64 fw = planes[o];
            const u64 q0 = planes[P + o];
            const u64 q1 = planes[2 * P + o];
            const u64 q2 = planes[3 * P + o];
            const u64 q3 = planes[4 * P + o];
            const u64 q4 = planes[5 * P + o];
            const size_t col = (size_t)(w2 << 6) + lane;
            const float fc = fcount[(size_t)r * WW + col];
            const int cv = (int)((q0 >> lane) & 1ull)
                         + ((int)((q1 >> lane) & 1ull) << 1)
                         + ((int)((q2 >> lane) & 1ull) << 2)
                         + ((int)((q3 >> lane) & 1ull) << 3)
                         + ((int)((q4 >> lane) & 1ull) << 4);
            float3 o3;
            o3.x = (float)((ow >> lane) & 1ull);
            o3.y = (float)((fw >> lane) & 1ull);
            o3.z = (float)cv + fc;
            *(float3*)(out + ((size_t)r * WW + col) * 3) = o3;
        }
    }
}

extern "C" void kernel_launch(void* const* d_in, const int* in_sizes, int n_in,
                              void* d_out, int out_size, void* d_ws, size_t ws_size,
                              hipStream_t stream) {
    const float* flood_input = (const float*)d_in[0];  // [4096][4096][2]
    const float* flood_cnt   = (const float*)d_in[1];  // [4096][4096]
    float* out = (float*)d_out;                        // [4096][4096][3]

    u64* occP   = (u64*)d_ws;                          // 2 MiB
    u64* flP    = occP + (size_t)WPR * HH;             // 2 MiB
    u64* planes = flP  + (size_t)WPR * HH;             // 12 MiB

    void* args[] = { (void*)&flood_input, (void*)&flood_cnt, (void*)&out,
                     (void*)&occP, (void*)&flP, (void*)&planes };
    hipLaunchCooperativeKernel((const void*)fused_kernel, dim3(NBLK), dim3(256),
                               args, 0, stream);
}

// Round 8
// 488.647 us; speedup vs baseline: 1.3330x; 1.3330x over previous
//
#include <hip/hip_runtime.h>

// FloodPath R8 (= R7 with compile fix): 3-kernel split, rebuilt expand.
//   K1 pack:   float2 [H][W][2] -> occ/flood bit planes, column-major [w][r].
//   K2 flood:  64x224 tiles, 16 bit-parallel dilation steps, writes 6 planes.
//   K3 expand: block = 4 consecutive rows, wave = 1 row, lane = 4 cells
//              (48 B) -> sequential aligned 16B stores, vec4 fcount loads,
//              nontemporal on the one-shot streams.
// Fix vs R7: __builtin_nontemporal_* requires native vector types, not
// HIP_vector_type — use ext_vector_type(4) float (f4) for those accesses.

typedef unsigned long long u64;
typedef float f4 __attribute__((ext_vector_type(4)));
typedef float f2 __attribute__((ext_vector_type(2)));

#define HH 4096
#define WW 4096
#define WPR 64            // u64 words per image row
#define NSTEPS 16
#define VROWS 224         // interior rows per flood block
#define RROWS 256         // region rows = VROWS + 2*16

// ---------------- K1: bitpack (column-major planes) ----------------
__global__ __launch_bounds__(256) void pack_kernel(
    const float* __restrict__ in, u64* __restrict__ occP, u64* __restrict__ flP)
{
    const int lane = threadIdx.x & 63;
    const int wv   = threadIdx.x >> 6;
    const int r    = blockIdx.x;                  // one image row per block
#pragma unroll
    for (int b = 0; b < 2; ++b) {
        float vx[8], vy[8];
#pragma unroll
        for (int j = 0; j < 8; ++j) {
            const int w = wv * 16 + b * 8 + j;
            const f2 v = __builtin_nontemporal_load(
                (const f2*)(in + ((size_t)r * WW + (w << 6) + lane) * 2));
            vx[j] = v.x; vy[j] = v.y;
        }
#pragma unroll
        for (int j = 0; j < 8; ++j) {
            const int w = wv * 16 + b * 8 + j;
            const u64 om = __ballot(vx[j] > 0.5f);
            const u64 fm = __ballot(vy[j] > 0.5f);
            if (lane == 0) {
                occP[(size_t)w * HH + r] = om;    // [w][r]
                flP [(size_t)w * HH + r] = fm;
            }
        }
    }
}

// ---------------- K2: flood iterate, packed in / packed out ----------------
__global__ __launch_bounds__(256) void flood_kernel(
    const u64* __restrict__ occP, const u64* __restrict__ flP,
    u64* __restrict__ planes)                     // [6][WPR][HH]
{
    __shared__ u64 bufA[RROWS * 2];
    __shared__ u64 bufB[RROWS * 2];

    const int tid = threadIdx.x;                  // region row
    const int w   = blockIdx.x;                   // interior word column
    const int gr  = blockIdx.y * VROWS + tid - 16;
    const bool rin = (gr >= 0) && (gr < HH);

    // Stage region row: 128 cols = [64w-16, 64w+112), 2 words via funnels.
    u64 oc[3], fl[3];
#pragma unroll
    for (int j = 0; j < 3; ++j) {
        const int q = w - 1 + j;
        const bool v = rin && (q >= 0) && (q < WPR);
        oc[j] = v ? occP[(size_t)q * HH + gr] : ~0ull;  // OOB => wall
        fl[j] = v ? flP [(size_t)q * HH + gr] : 0ull;
    }
    const u64 nocc0 = ~((oc[0] >> 48) | (oc[1] << 16));
    const u64 nocc1 = ~((oc[1] >> 48) | (oc[2] << 16));
    u64 f0 = (fl[0] >> 48) | (fl[1] << 16);
    u64 f1 = (fl[1] >> 48) | (fl[2] << 16);

    u64 c00 = 0, c01 = 0, c02 = 0, c03 = 0, c04 = 0;
    u64 c10 = 0, c11 = 0, c12 = 0, c13 = 0, c14 = 0;

    bufA[tid * 2 + 0] = f0; bufA[tid * 2 + 1] = f1;
    __syncthreads();

    u64* cur = bufA;
    u64* nxt = bufB;
    for (int it = 0; it < NSTEPS; ++it) {
        u64 up0 = 0, up1 = 0, dn0 = 0, dn1 = 0;
        if (tid > 0)         { up0 = cur[(tid - 1) * 2 + 0]; up1 = cur[(tid - 1) * 2 + 1]; }
        if (tid < RROWS - 1) { dn0 = cur[(tid + 1) * 2 + 0]; dn1 = cur[(tid + 1) * 2 + 1]; }
        const u64 nf0 = nocc0 & (f0 | (f0 << 1) | (f0 >> 1) | (f1 << 63) | up0 | dn0);
        const u64 nf1 = nocc1 & (f1 | (f1 << 1) | (f0 >> 63) | (f1 >> 1) | up1 | dn1);
        u64 c, t;
        c = nf0;
        t = c00; c00 = t ^ c; c = t & c;
        t = c01; c01 = t ^ c; c = t & c;
        t = c02; c02 = t ^ c; c = t & c;
        t = c03; c03 = t ^ c; c = t & c;
        c04 ^= c;                                  // max 16: no carry out
        c = nf1;
        t = c10; c10 = t ^ c; c = t & c;
        t = c11; c11 = t ^ c; c = t & c;
        t = c12; c12 = t ^ c; c = t & c;
        t = c13; c13 = t ^ c; c = t & c;
        c14 ^= c;
        nxt[tid * 2 + 0] = nf0; nxt[tid * 2 + 1] = nf1;
        f0 = nf0; f1 = nf1;
        __syncthreads();
        u64* tmp = cur; cur = nxt; nxt = tmp;
    }

    // Interior word = region bits [16,80): coalesced 8B/lane column-major.
    if (tid >= 16 && tid < 16 + VROWS && gr < HH) {
        const size_t o = (size_t)w * HH + gr;
        const size_t P = (size_t)WPR * HH;
        planes[o]         = (f0  >> 16) | (f1  << 48);
        planes[P + o]     = (c00 >> 16) | (c10 << 48);
        planes[2 * P + o] = (c01 >> 16) | (c11 << 48);
        planes[3 * P + o] = (c02 >> 16) | (c12 << 48);
        planes[4 * P + o] = (c03 >> 16) | (c13 << 48);
        planes[5 * P + o] = (c04 >> 16) | (c14 << 48);
    }
}

// ---------------- K3: expand — fill-shaped sequential stream ----------------
// Block = 4 consecutive rows; wave = 1 row; lane = 4 cells = 48 B out.
__global__ __launch_bounds__(256) void expand_kernel(
    const u64* __restrict__ occP, const u64* __restrict__ planes,
    const float* __restrict__ fcount, float* __restrict__ out)
{
    const int lane = threadIdx.x & 63;
    const int wv   = threadIdx.x >> 6;
    const int r    = blockIdx.x * 4 + wv;         // my output row
    const size_t P = (size_t)WPR * HH;
    const int qlo  = lane >> 4;                   // word sub-index 0..3
    const int bit0 = (lane & 15) << 2;            // my 4 bits within the word

    const f4* __restrict__ fc4 = (const f4*)fcount;
    f4* __restrict__ out4 = (f4*)out;

#pragma unroll 2
    for (int i = 0; i < 16; ++i) {                // 256 cells per wave-iter
        const int q = (i << 2) + qlo;             // word index along the row
        const size_t o = (size_t)q * HH + r;
        const u64 ow = occP[o];
        const u64 fw = planes[o];
        const u64 q0 = planes[P + o];
        const u64 q1 = planes[2 * P + o];
        const u64 q2 = planes[3 * P + o];
        const u64 q3 = planes[4 * P + o];
        const u64 q4 = planes[5 * P + o];
        const f4 fc = __builtin_nontemporal_load(
            fc4 + (size_t)r * (WW / 4) + (i << 6) + lane);

        float v[12];
        const float fcv[4] = { fc.x, fc.y, fc.z, fc.w };
#pragma unroll
        for (int j = 0; j < 4; ++j) {
            const int b = bit0 + j;
            const int cv = (int)((q0 >> b) & 1ull)
                         + ((int)((q1 >> b) & 1ull) << 1)
                         + ((int)((q2 >> b) & 1ull) << 2)
                         + ((int)((q3 >> b) & 1ull) << 3)
                         + ((int)((q4 >> b) & 1ull) << 4);
            v[j * 3 + 0] = (float)((ow >> b) & 1ull);
            v[j * 3 + 1] = (float)((fw >> b) & 1ull);
            v[j * 3 + 2] = (float)cv + fcv[j];
        }
        // 12 floats = 3 aligned 16B stores at 48B/lane.
        const size_t base = (size_t)r * (WW * 3 / 4) + (size_t)i * 192 + lane * 3;
        f4 s0; s0.x = v[0]; s0.y = v[1]; s0.z = v[2];  s0.w = v[3];
        f4 s1; s1.x = v[4]; s1.y = v[5]; s1.z = v[6];  s1.w = v[7];
        f4 s2; s2.x = v[8]; s2.y = v[9]; s2.z = v[10]; s2.w = v[11];
        __builtin_nontemporal_store(s0, out4 + base);
        __builtin_nontemporal_store(s1, out4 + base + 1);
        __builtin_nontemporal_store(s2, out4 + base + 2);
    }
}

extern "C" void kernel_launch(void* const* d_in, const int* in_sizes, int n_in,
                              void* d_out, int out_size, void* d_ws, size_t ws_size,
                              hipStream_t stream) {
    const float* flood_input = (const float*)d_in[0];  // [4096][4096][2]
    const float* flood_cnt   = (const float*)d_in[1];  // [4096][4096]
    float* out = (float*)d_out;                        // [4096][4096][3]

    u64* occP   = (u64*)d_ws;                          // 2 MiB
    u64* flP    = occP + (size_t)WPR * HH;             // 2 MiB
    u64* planes = flP  + (size_t)WPR * HH;             // 12 MiB

    pack_kernel<<<dim3(HH), dim3(256), 0, stream>>>(flood_input, occP, flP);
    flood_kernel<<<dim3(WPR, (HH + VROWS - 1) / VROWS), dim3(256), 0, stream>>>(
        occP, flP, planes);
    expand_kernel<<<dim3(HH / 4), dim3(256), 0, stream>>>(
        occP, planes, flood_cnt, out);
}